// Round 13
// baseline (272.554 us; speedup 1.0000x reference)
//
#include <hip/hip_runtime.h>
#include <math.h>

constexpr int Bc = 32;     // batch
constexpr int Tc = 1000;   // time
constexpr int Vc = 1024;   // vocab
constexpr int Lc = 128;    // label length
constexpr int Sc = 2 * Lc + 1;  // 257 lattice states
constexpr int SPq = 256;        // stride: [lane][4] layout (64*4 floats = 1 KB/row)
constexpr float NEGF = -1e30f;
constexpr float L2E = 1.4426950408889634f;   // log2(e)
constexpr float LN2 = 0.6931471805599453f;   // ln(2)
constexpr int ENEG = -(1 << 24);             // sentinel exponent: "no mass"

#if __has_builtin(__builtin_amdgcn_exp2f)
#define EXP2F(x) __builtin_amdgcn_exp2f(x)
#else
#define EXP2F(x) exp2f(x)
#endif
#if __has_builtin(__builtin_amdgcn_logf)
#define LOG2F(x) __builtin_amdgcn_logf(x)
#else
#define LOG2F(x) log2f(x)
#endif
#if __has_builtin(__builtin_amdgcn_ldexpf)
#define LDEXPF(x, e) __builtin_amdgcn_ldexpf(x, e)
#else
#define LDEXPF(x, e) ldexpf(x, e)
#endif
#if __has_builtin(__builtin_amdgcn_frexp_expf)
#define FREXPE(x) __builtin_amdgcn_frexp_expf(x)
#else
__device__ inline int FREXPE(float x) { int e; (void)frexpf(x, &e); return e; }
#endif

// DPP wave_shr:1 — lane l receives lane l-1's value; lane 0 gets 0
// (bound_ctrl=1). VALU-latency cross-lane move. Verified bit-exact (R4/R11).
__device__ __forceinline__ float dpp_wave_shr1(float x) {
  return __int_as_float(__builtin_amdgcn_update_dpp(
      0, __float_as_int(x), 0x138 /* wave_shr:1 */, 0xf, 0xf, true));
}
__device__ __forceinline__ int dpp_wave_shr1_i(int x) {
  return __builtin_amdgcn_update_dpp(0, x, 0x138 /* wave_shr:1 */, 0xf, 0xf, true);
}

// Async global->LDS: per-lane global src, wave-uniform LDS base; HW writes
// lane's 16 B at base + lane*16 (guide §5, m97/m104). Counted by vmcnt.
__device__ __forceinline__ void gload_lds16(const float* g, float* l) {
  __builtin_amdgcn_global_load_lds(
      (const __attribute__((address_space(1))) void*)g,
      (__attribute__((address_space(3))) void*)l, 16, 0, 0);
}
// Explicit counted waits; "memory" clobber stops ds_reads hoisting above.
#define WAITV(n) asm volatile("s_waitcnt vmcnt(" #n ")" ::: "memory")

// Layout: lpe[bt][lane*4 + j]:
//   j=0: pblank (serves states 4l and 4l+2 — identical value)
//   j=1: p(label y[2l])    (state 4l+1)
//   j=2: p(label y[2l+1])  (state 4l+3)
//   j=3: lane==63 ? pblank : 0   (state 256)
// One float4 per lane per step. Values LINEAR.

// ---------------------------------------------------------------------------
// Kernel A: log-softmax + gather, one WAVE per (b,t) row; one float4 store
// per lane in the [lane][4] layout. Also zeroes the fused output scalar
// (runs before ctc_alpha on the stream, so the zero lands before atomics).
// ---------------------------------------------------------------------------
__global__ __launch_bounds__(256) void ctc_lse_gather(
    const float* __restrict__ hs, const int* __restrict__ ys,
    float* __restrict__ lpe, float* __restrict__ out) {
  if (blockIdx.x == 0 && threadIdx.x == 0) out[0] = 0.f;
  const int wv = threadIdx.x >> 6;
  const int lane = threadIdx.x & 63;
  const int bt = blockIdx.x * 4 + wv;   // row index b*Tc + t
  const int b = bt / Tc;
  const float* row = hs + (size_t)bt * Vc;

  __shared__ float xs_all[4][Vc];
  float* xs = xs_all[wv];

  float4 v[4];
#pragma unroll
  for (int q = 0; q < 4; ++q) v[q] = reinterpret_cast<const float4*>(row)[lane + 64 * q];
#pragma unroll
  for (int q = 0; q < 4; ++q) { v[q].x *= L2E; v[q].y *= L2E; v[q].z *= L2E; v[q].w *= L2E; }

  float m = -3.4e38f;
#pragma unroll
  for (int q = 0; q < 4; ++q)
    m = fmaxf(m, fmaxf(fmaxf(v[q].x, v[q].y), fmaxf(v[q].z, v[q].w)));
#pragma unroll
  for (int off = 32; off; off >>= 1) m = fmaxf(m, __shfl_xor(m, off, 64));

  float sum = 0.f;
#pragma unroll
  for (int q = 0; q < 4; ++q)
    sum += EXP2F(v[q].x - m) + EXP2F(v[q].y - m) + EXP2F(v[q].z - m) + EXP2F(v[q].w - m);
#pragma unroll
  for (int off = 32; off; off >>= 1) sum += __shfl_xor(sum, off, 64);
  const float lse2 = m + LOG2F(sum);

#pragma unroll
  for (int q = 0; q < 4; ++q) reinterpret_cast<float4*>(xs)[lane + 64 * q] = v[q];
  __syncthreads();

  const int la1 = ys[b * Lc + 2 * lane];         // state 4l+1
  const int la3 = ys[b * Lc + 2 * lane + 1];     // state 4l+3
  float4 o;
  o.x = EXP2F(xs[0] - lse2);                     // blank (states 4l, 4l+2)
  o.y = EXP2F(xs[la1] - lse2);
  o.z = EXP2F(xs[la3] - lse2);
  o.w = (lane == 63) ? o.x : 0.f;                // state 256 (last blank)
  reinterpret_cast<float4*>(lpe + (size_t)bt * SPq)[lane] = o;
}

// ---------------------------------------------------------------------------
// Kernel B: CTC alpha, LINEAR domain, per-lane integer exponent reconciled
// once per 8-step GROUP. Load path: global_load_lds dwordx4 into a 5-slot
// LDS ring (8 KB/group), explicit counted s_waitcnt vmcnt(N) — never 0 in
// steady state (R12 post-mortem: VGPR-ring depth-3 gave 0 gain because the
// compiler's waitcnt insertion collapsed the pipeline; explicit vmcnt takes
// that control back — guide T3/T4). Batch-mean fused via atomicAdd.
// ---------------------------------------------------------------------------
__global__ __launch_bounds__(64) void ctc_alpha(
    const float* __restrict__ lpe, const int* __restrict__ ys,
    const int* __restrict__ hlen, const int* __restrict__ ylen,
    float* __restrict__ out) {
  const int b = blockIdx.x;
  const int lane = threadIdx.x;
  const float* pb = lpe + (size_t)b * Tc * SPq;
  const float* pl = pb + lane * 4;                 // per-lane base
  const int* yb = ys + b * Lc;

  __shared__ float ring[5][8][SPq];               // 5 group slots x 8 rows x 1 KB

  // skip factors (wave-uniform slot parity)
  const float sk1 = (lane >= 1 && yb[2 * lane - 1] != yb[2 * lane]) ? 1.f : 0.f;
  const float sk3 = (yb[2 * lane] != yb[2 * lane + 1]) ? 1.f : 0.f;

  // t=0: state 0 (lane0 j0 = pblank), state 1 (lane0 j1 = p(y[0]))
  float m0 = (lane == 0) ? pb[0] : 0.f;
  float m1 = (lane == 0) ? pb[1] : 0.f;
  float m2 = 0.f, m3 = 0.f, m4 = 0.f;
  int E = (lane == 0) ? 0 : ENEG;     // sentinel: no mass on this lane yet
  float fsh = 0.f;                    // neighbor-scale factor, set by renorm()

  const int Te = min(hlen[b], Tc);

  auto renorm = [&]() {
    const float mx = fmaxf(fmaxf(fmaxf(m0, m1), fmaxf(m2, m3)), m4);
    const int e = FREXPE(mx);                 // mx = mant * 2^e, mant in [0.5,1)
    const int E1 = (mx > 0.f) ? E + e : ENEG; // true exponent of lane max
    int Eup = dpp_wave_shr1_i(E1);            // lane 0 gets 0 from bound_ctrl...
    if (lane == 0) Eup = ENEG;                // ...remap to the empty sentinel
    const int En = max(E1, Eup);              // working scale for next group
    const int dm = E - En;                    // rescale my mantissas to En
    fsh = LDEXPF(1.f, Eup - En);              // <=1; 0 if neighbor empty
    m0 = LDEXPF(m0, dm);
    m1 = LDEXPF(m1, dm);
    m2 = LDEXPF(m2, dm);
    m3 = LDEXPF(m3, dm);
    m4 = LDEXPF(m4, dm);
    E = En;
  };

  // Per-step body: one DPP on the cross-lane path; p0=v.x, p1=v.y, p2=v.x,
  // p3=v.z, p4=v.w (bit-identical to the 5-slot form: old p2 == old p0).
  auto step = [&](const float4 v) {
    const float msh = dpp_wave_shr1(m3);   // state 4l-1 from lane l-1 (0 on lane 0)
    const float am = msh * fsh;            // at my scale
    const float n0 = (m0 + am) * v.x;                  // blank
    const float n1 = fmaf(sk1, am, m1 + m0) * v.y;     // label y[2l]
    const float n2 = (m2 + m1) * v.x;                  // blank
    const float n3 = fmaf(sk3, m1, m3 + m2) * v.z;     // label y[2l+1]
    const float n4 = (m4 + m3) * v.w;                  // last blank (lane 63)
    m0 = n0; m1 = n1; m2 = n2; m3 = n3; m4 = n4;
  };

  // issue one group's 8 async loads into its ring slot (8 vmcnt events)
  auto issue8 = [&](int gi) {
    const int s = gi % 5;
    const float* p_ = pl + (size_t)(1 + 8 * gi) * SPq;
#pragma unroll
    for (int k = 0; k < 8; ++k)
      gload_lds16(p_ + (size_t)k * SPq, &ring[s][k][0]);
  };
  // consume one group from its ring slot
  auto step8 = [&](int g) {
    const int s = g % 5;
    renorm();
#pragma unroll
    for (int k = 0; k < 8; ++k) {
      const float4 v = reinterpret_cast<const float4*>(&ring[s][k][0])[lane];
      step(v);
    }
  };

  // groups: group gi covers rows [1+8gi, 8+8gi]; G full groups in [1, Te-1].
  // Depth-4 pipeline: wait vmcnt((inflight-1)*8) => oldest group landed
  // (FIFO retirement); issue next group BEFORE computing so loads overlap.
  const int G = (Te - 1) / 8;
  int issued = 0;
  for (; issued < G && issued < 4; ++issued) issue8(issued);
  for (int g = 0; g < G; ++g) {
    const int inflight = issued - g;        // 1..4
    if (inflight >= 4)      WAITV(24);
    else if (inflight == 3) WAITV(16);
    else if (inflight == 2) WAITV(8);
    else                    WAITV(0);
    if (issued < G) { issue8(issued); ++issued; }
    step8(g);
  }
  // tail: R = Te - (1+8G) rows (< 8); direct reg loads then step
  {
    const int t0 = 1 + 8 * G;
    const int R = Te - t0;                  // wave-uniform
    float4 bt[7];
#pragma unroll
    for (int k = 0; k < 7; ++k)
      if (k < R) bt[k] = *reinterpret_cast<const float4*>(pl + (size_t)(t0 + k) * SPq);
#pragma unroll
    for (int k = 0; k < 7; ++k)
      if (k < R) { renorm(); step(bt[k]); }
  }

  // final: loss = -ln2 * log2(alpha[2L] + alpha[2L-1]) / ylen, scales exact;
  // batch mean via one atomicAdd per block (out zeroed by kernel A).
  __shared__ float msm[Sc];
  __shared__ int esm[64];
#pragma unroll
  for (int j = 0; j < 4; ++j) msm[4 * lane + j] = (j == 0 ? m0 : j == 1 ? m1 : j == 2 ? m2 : m3);
  if (lane == 63) msm[256] = m4;
  esm[lane] = E;
  __syncthreads();
  if (lane == 0) {
    const int yl = ylen[b];
    const int s1 = 2 * yl, s0 = 2 * yl - 1;
    const int l1 = (s1 == 256) ? 63 : (s1 >> 2);
    const int l0 = s0 >> 2;
    const float vx = msm[s1]; const int ex = esm[l1];
    const float vy = msm[s0]; const int ey = esm[l0];
    const int Em = max(ex, ey);
    const float rr = LDEXPF(vx, ex - Em) + LDEXPF(vy, ey - Em);
    const float ae2 = (rr > 0.f) ? (LOG2F(rr) + (float)Em) : NEGF;
    atomicAdd(out, -(ae2 * LN2) / ((float)yl * (float)Bc));
  }
}

extern "C" void kernel_launch(void* const* d_in, const int* in_sizes, int n_in,
                              void* d_out, int out_size, void* d_ws, size_t ws_size,
                              hipStream_t stream) {
  const float* hs = (const float*)d_in[0];    // (B,T,V) fp32
  const int* hlen = (const int*)d_in[1];      // (B,)
  const int* ys = (const int*)d_in[2];        // (B,L)
  const int* ylen = (const int*)d_in[3];      // (B,)
  float* out = (float*)d_out;                 // scalar

  float* lpe = (float*)d_ws;                  // B*T*SPq floats (~32.8 MB)

  ctc_lse_gather<<<Bc * Tc / 4, 256, 0, stream>>>(hs, ys, lpe, out);
  ctc_alpha<<<Bc, 64, 0, stream>>>(lpe, ys, hlen, ylen, out);
}

// Round 14
// 231.985 us; speedup vs baseline: 1.1749x; 1.1749x over previous
//
#include <hip/hip_runtime.h>
#include <math.h>

constexpr int Bc = 32;     // batch
constexpr int Tc = 1000;   // time
constexpr int Vc = 1024;   // vocab
constexpr int Lc = 128;    // label length
constexpr int Sc = 2 * Lc + 1;  // 257 lattice states
constexpr int SPq = 256;        // stride: [lane][4] layout (64*4 floats = 1 KB/row)
constexpr float NEGF = -1e30f;
constexpr float L2E = 1.4426950408889634f;   // log2(e)
constexpr float LN2 = 0.6931471805599453f;   // ln(2)
constexpr int ENEG = -(1 << 24);             // sentinel exponent: "no mass"

#if __has_builtin(__builtin_amdgcn_exp2f)
#define EXP2F(x) __builtin_amdgcn_exp2f(x)
#else
#define EXP2F(x) exp2f(x)
#endif
#if __has_builtin(__builtin_amdgcn_logf)
#define LOG2F(x) __builtin_amdgcn_logf(x)
#else
#define LOG2F(x) log2f(x)
#endif
#if __has_builtin(__builtin_amdgcn_ldexpf)
#define LDEXPF(x, e) __builtin_amdgcn_ldexpf(x, e)
#else
#define LDEXPF(x, e) ldexpf(x, e)
#endif
#if __has_builtin(__builtin_amdgcn_frexp_expf)
#define FREXPE(x) __builtin_amdgcn_frexp_expf(x)
#else
__device__ inline int FREXPE(float x) { int e; (void)frexpf(x, &e); return e; }
#endif

// DPP wave_shr:1 — lane l receives lane l-1's value; lane 0 gets 0
// (bound_ctrl=1). VALU-latency cross-lane move. Verified bit-exact (R4/R11).
__device__ __forceinline__ float dpp_wave_shr1(float x) {
  return __int_as_float(__builtin_amdgcn_update_dpp(
      0, __float_as_int(x), 0x138 /* wave_shr:1 */, 0xf, 0xf, true));
}
__device__ __forceinline__ int dpp_wave_shr1_i(int x) {
  return __builtin_amdgcn_update_dpp(0, x, 0x138 /* wave_shr:1 */, 0xf, 0xf, true);
}

// Layout: lpe[bt][lane*4 + j]:
//   j=0: pblank (serves states 4l and 4l+2 — identical value)
//   j=1: p(label y[2l])    (state 4l+1)
//   j=2: p(label y[2l+1])  (state 4l+3)
//   j=3: lane==63 ? pblank : 0   (state 256)
// One float4 per lane per step. Values LINEAR.

// ---------------------------------------------------------------------------
// Kernel A: log-softmax + gather, one WAVE per (b,t) row; one float4 store
// per lane in the [lane][4] layout. Also zeroes the fused output scalar
// (runs before ctc_alpha on the stream, so the zero lands before atomics).
// ---------------------------------------------------------------------------
__global__ __launch_bounds__(256) void ctc_lse_gather(
    const float* __restrict__ hs, const int* __restrict__ ys,
    float* __restrict__ lpe, float* __restrict__ out) {
  if (blockIdx.x == 0 && threadIdx.x == 0) out[0] = 0.f;
  const int wv = threadIdx.x >> 6;
  const int lane = threadIdx.x & 63;
  const int bt = blockIdx.x * 4 + wv;   // row index b*Tc + t
  const int b = bt / Tc;
  const float* row = hs + (size_t)bt * Vc;

  __shared__ float xs_all[4][Vc];
  float* xs = xs_all[wv];

  float4 v[4];
#pragma unroll
  for (int q = 0; q < 4; ++q) v[q] = reinterpret_cast<const float4*>(row)[lane + 64 * q];
#pragma unroll
  for (int q = 0; q < 4; ++q) { v[q].x *= L2E; v[q].y *= L2E; v[q].z *= L2E; v[q].w *= L2E; }

  float m = -3.4e38f;
#pragma unroll
  for (int q = 0; q < 4; ++q)
    m = fmaxf(m, fmaxf(fmaxf(v[q].x, v[q].y), fmaxf(v[q].z, v[q].w)));
#pragma unroll
  for (int off = 32; off; off >>= 1) m = fmaxf(m, __shfl_xor(m, off, 64));

  float sum = 0.f;
#pragma unroll
  for (int q = 0; q < 4; ++q)
    sum += EXP2F(v[q].x - m) + EXP2F(v[q].y - m) + EXP2F(v[q].z - m) + EXP2F(v[q].w - m);
#pragma unroll
  for (int off = 32; off; off >>= 1) sum += __shfl_xor(sum, off, 64);
  const float lse2 = m + LOG2F(sum);

#pragma unroll
  for (int q = 0; q < 4; ++q) reinterpret_cast<float4*>(xs)[lane + 64 * q] = v[q];
  __syncthreads();

  const int la1 = ys[b * Lc + 2 * lane];         // state 4l+1
  const int la3 = ys[b * Lc + 2 * lane + 1];     // state 4l+3
  float4 o;
  o.x = EXP2F(xs[0] - lse2);                     // blank (states 4l, 4l+2)
  o.y = EXP2F(xs[la1] - lse2);
  o.z = EXP2F(xs[la3] - lse2);
  o.w = (lane == 63) ? o.x : 0.f;                // state 256 (last blank)
  reinterpret_cast<float4*>(lpe + (size_t)bt * SPq)[lane] = o;
}

// ---------------------------------------------------------------------------
// Kernel B: CTC alpha, LINEAR domain, per-lane integer exponent reconciled
// once per 8-step GROUP. Load path: VGPR 4-buffer float4 ring, depth 3, with
// load issue interleaved 1:1 into the step stream (AITER pattern). R13
// post-mortem: LDS ring regressed (84.5 µs). R11/R12 neutrality of depth
// suggests sched_barrier(0) made the waitcnt pass drain per group; removing
// it and interleaving gives the compiler a ~360-instruction load->use
// distance to emit counted vmcnt waits. Batch-mean fused via atomicAdd.
// ---------------------------------------------------------------------------
__global__ __launch_bounds__(64) void ctc_alpha(
    const float* __restrict__ lpe, const int* __restrict__ ys,
    const int* __restrict__ hlen, const int* __restrict__ ylen,
    float* __restrict__ out) {
  const int b = blockIdx.x;
  const int lane = threadIdx.x;
  const float* pb = lpe + (size_t)b * Tc * SPq;
  const float* pl = pb + lane * 4;                 // per-lane base
  const int* yb = ys + b * Lc;

  // skip factors (wave-uniform slot parity)
  const float sk1 = (lane >= 1 && yb[2 * lane - 1] != yb[2 * lane]) ? 1.f : 0.f;
  const float sk3 = (yb[2 * lane] != yb[2 * lane + 1]) ? 1.f : 0.f;

  // t=0: state 0 (lane0 j0 = pblank), state 1 (lane0 j1 = p(y[0]))
  float m0 = (lane == 0) ? pb[0] : 0.f;
  float m1 = (lane == 0) ? pb[1] : 0.f;
  float m2 = 0.f, m3 = 0.f, m4 = 0.f;
  int E = (lane == 0) ? 0 : ENEG;     // sentinel: no mass on this lane yet
  float fsh = 0.f;                    // neighbor-scale factor, set by renorm()

  const int Te = min(hlen[b], Tc);

  auto renorm = [&]() {
    const float mx = fmaxf(fmaxf(fmaxf(m0, m1), fmaxf(m2, m3)), m4);
    const int e = FREXPE(mx);                 // mx = mant * 2^e, mant in [0.5,1)
    const int E1 = (mx > 0.f) ? E + e : ENEG; // true exponent of lane max
    int Eup = dpp_wave_shr1_i(E1);            // lane 0 gets 0 from bound_ctrl...
    if (lane == 0) Eup = ENEG;                // ...remap to the empty sentinel
    const int En = max(E1, Eup);              // working scale for next group
    const int dm = E - En;                    // rescale my mantissas to En
    fsh = LDEXPF(1.f, Eup - En);              // <=1; 0 if neighbor empty
    m0 = LDEXPF(m0, dm);
    m1 = LDEXPF(m1, dm);
    m2 = LDEXPF(m2, dm);
    m3 = LDEXPF(m3, dm);
    m4 = LDEXPF(m4, dm);
    E = En;
  };

  // Per-step body: one DPP on the cross-lane path; p0=v.x, p1=v.y, p2=v.x,
  // p3=v.z, p4=v.w (bit-identical to the 5-slot form: old p2 == old p0).
  auto step = [&](const float4 v) {
    const float msh = dpp_wave_shr1(m3);   // state 4l-1 from lane l-1 (0 on lane 0)
    const float am = msh * fsh;            // at my scale
    const float n0 = (m0 + am) * v.x;                  // blank
    const float n1 = fmaf(sk1, am, m1 + m0) * v.y;     // label y[2l]
    const float n2 = (m2 + m1) * v.x;                  // blank
    const float n3 = fmaf(sk3, m1, m3 + m2) * v.z;     // label y[2l+1]
    const float n4 = (m4 + m3) * v.w;                  // last blank (lane 63)
    m0 = n0; m1 = n1; m2 = n2; m3 = n3; m4 = n4;
  };

  float4 bufA[8], bufB[8], bufC[8], bufD[8];
#define ROW(GI, K) (*reinterpret_cast<const float4*>(pl + (size_t)(1 + 8 * (GI) + (K)) * SPq))
#define LOAD8(BUF, GI)                                                        \
  do {                                                                        \
    _Pragma("unroll") for (int k_ = 0; k_ < 8; ++k_) BUF[k_] = ROW(GI, k_);   \
  } while (0)
#define STEP8(BUF)                                                            \
  do {                                                                        \
    renorm();                                                                 \
    _Pragma("unroll") for (int k_ = 0; k_ < 8; ++k_) step(BUF[k_]);           \
  } while (0)
// Consume CUR while issuing group GI into DST, 1 load : 1 step interleave.
#define STEPLOAD8(CUR, DST, GI)                                               \
  do {                                                                        \
    renorm();                                                                 \
    _Pragma("unroll") for (int k_ = 0; k_ < 8; ++k_) {                        \
      DST[k_] = ROW(GI, k_);                                                  \
      step(CUR[k_]);                                                          \
    }                                                                         \
  } while (0)

  // groups: group gi covers rows [1+8gi, 8+8gi]; G full groups in [1, Te-1].
  // 4-buffer ring, depth 3; consumption order identical to R12 (audited for
  // G mod 4 exits and G in 0..8).
  const int G = (Te - 1) / 8;
  int g = 0;
  if (G > 0) LOAD8(bufA, 0);
  if (G > 1) LOAD8(bufB, 1);
  if (G > 2) LOAD8(bufC, 2);
  while (g + 4 <= G) {
    STEPLOAD8(bufA, bufD, g + 3);           // g+3 <= G-1 here
    if (g + 4 < G) STEPLOAD8(bufB, bufA, g + 4); else STEP8(bufB);
    if (g + 5 < G) STEPLOAD8(bufC, bufB, g + 5); else STEP8(bufC);
    if (g + 6 < G) STEPLOAD8(bufD, bufC, g + 6); else STEP8(bufD);
    g += 4;
  }
  // 0..3 fully-loaded groups remain in phase order A, B, C
  const int r = G - g;
  if (r >= 1) STEP8(bufA);
  if (r >= 2) STEP8(bufB);
  if (r >= 3) STEP8(bufC);
  // tail: R = Te - (1+8G) rows (< 8); batch-load into bufD then step
  {
    const int t0 = 1 + 8 * G;
    const int R = Te - t0;                  // wave-uniform
#pragma unroll
    for (int k = 0; k < 7; ++k)
      if (k < R) bufD[k] = *reinterpret_cast<const float4*>(pl + (size_t)(t0 + k) * SPq);
#pragma unroll
    for (int k = 0; k < 7; ++k)
      if (k < R) { renorm(); step(bufD[k]); }
  }
#undef STEPLOAD8
#undef STEP8
#undef LOAD8
#undef ROW

  // final: loss = -ln2 * log2(alpha[2L] + alpha[2L-1]) / ylen, scales exact;
  // batch mean via one atomicAdd per block (out zeroed by kernel A).
  __shared__ float msm[Sc];
  __shared__ int esm[64];
#pragma unroll
  for (int j = 0; j < 4; ++j) msm[4 * lane + j] = (j == 0 ? m0 : j == 1 ? m1 : j == 2 ? m2 : m3);
  if (lane == 63) msm[256] = m4;
  esm[lane] = E;
  __syncthreads();
  if (lane == 0) {
    const int yl = ylen[b];
    const int s1 = 2 * yl, s0 = 2 * yl - 1;
    const int l1 = (s1 == 256) ? 63 : (s1 >> 2);
    const int l0 = s0 >> 2;
    const float vx = msm[s1]; const int ex = esm[l1];
    const float vy = msm[s0]; const int ey = esm[l0];
    const int Em = max(ex, ey);
    const float rr = LDEXPF(vx, ex - Em) + LDEXPF(vy, ey - Em);
    const float ae2 = (rr > 0.f) ? (LOG2F(rr) + (float)Em) : NEGF;
    atomicAdd(out, -(ae2 * LN2) / ((float)yl * (float)Bc));
  }
}

extern "C" void kernel_launch(void* const* d_in, const int* in_sizes, int n_in,
                              void* d_out, int out_size, void* d_ws, size_t ws_size,
                              hipStream_t stream) {
  const float* hs = (const float*)d_in[0];    // (B,T,V) fp32
  const int* hlen = (const int*)d_in[1];      // (B,)
  const int* ys = (const int*)d_in[2];        // (B,L)
  const int* ylen = (const int*)d_in[3];      // (B,)
  float* out = (float*)d_out;                 // scalar

  float* lpe = (float*)d_ws;                  // B*T*SPq floats (~32.8 MB)

  ctc_lse_gather<<<Bc * Tc / 4, 256, 0, stream>>>(hs, ys, lpe, out);
  ctc_alpha<<<Bc, 64, 0, stream>>>(lpe, ys, hlen, ylen, out);
}